// Round 5
// baseline (367.967 us; speedup 1.0000x reference)
//
#include <hip/hip_runtime.h>
#include <hip/hip_bf16.h>
#include <stdint.h>

#define N 8192
#define D 512
#define TILE 128
#define BK 64
#define NKC (D / BK)                  // 8 K-chunks
#define NTB (N / TILE)                // 64 tile-rows
#define NBLK (NTB * (NTB + 1) / 2)    // 2080 upper-tri blocks
#define PANEL_ELEMS (TILE * D)        // 65536 elems = 128 KB per 128-row panel
#define KCHUNK_ELEMS (TILE * BK)      // 8192 elems = 16 KB per staged tile

typedef __attribute__((ext_vector_type(8))) short bf16x8;
typedef __attribute__((ext_vector_type(4))) float f32x4;

// async global->LDS, 16B per lane; LDS dest = wave-uniform base + lane*16
__device__ __forceinline__ void gload_lds16(const void* gp, const void* lp) {
    auto g = (const __attribute__((address_space(1))) void*)(uintptr_t)gp;
    auto l = (__attribute__((address_space(3))) void*)(uintptr_t)lp;
    __builtin_amdgcn_global_load_lds(g, l, 16, 0, 0);
}

__device__ __forceinline__ short f2bf(float x) {
    uint32_t u = __float_as_uint(x);
    u += 0x7fffu + ((u >> 16) & 1u);   // RNE; inputs finite/small
    return (short)(u >> 16);
}

// Fn2 swizzled layout = the LDS tile image, linearized:
//   elem(p, kc, sub, lr, ko) = p*65536 + ((kc*8 + sub)*128 + lr)*8 + ko
// where p = row>>7 (panel), lr = row&127, k = kc*64 + sub*8 + ko.
// -> staging a (panel,kc) tile is a LINEAR 16 KB copy (perfectly coalesced,
//    legal global_load_lds dest), and frag reads in LDS are conflict-free.

// one wave per row: fp32 row -> L2-normalized bf16, swizzled store.
// Blocks 0..15 zero tot/pos; block 16 zeroes the done-counter.
__global__ void cc_normalize(const float* __restrict__ F, short* __restrict__ Fn2,
                             float* __restrict__ totpos, int* __restrict__ cnt) {
    if (blockIdx.x < 16)
        ((float4*)totpos)[blockIdx.x * 256 + threadIdx.x] = make_float4(0.f, 0.f, 0.f, 0.f);
    if (blockIdx.x == 16 && threadIdx.x == 0) *cnt = 0;

    const int row  = blockIdx.x * 4 + (threadIdx.x >> 6);
    const int lane = threadIdx.x & 63;      // lane covers k = lane*8 .. +7
    const float* p = F + (size_t)row * D + lane * 8;
    float4 a = *(const float4*)p;
    float4 b = *(const float4*)(p + 4);
    float ss = a.x*a.x + a.y*a.y + a.z*a.z + a.w*a.w
             + b.x*b.x + b.y*b.y + b.z*b.z + b.w*b.w;
    #pragma unroll
    for (int m = 32; m; m >>= 1) ss += __shfl_xor(ss, m, 64);
    const float inv = 1.0f / fmaxf(sqrtf(ss), 1e-12f);
    bf16x8 o;
    o[0] = f2bf(a.x*inv); o[1] = f2bf(a.y*inv); o[2] = f2bf(a.z*inv); o[3] = f2bf(a.w*inv);
    o[4] = f2bf(b.x*inv); o[5] = f2bf(b.y*inv); o[6] = f2bf(b.z*inv); o[7] = f2bf(b.w*inv);
    // kc*8+sub == lane  ->  idx = panel*65536 + lane*1024 + (row&127)*8
    const size_t idx = (size_t)(row >> 7) * PANEL_ELEMS + (size_t)lane * 1024 + (row & 127) * 8;
    *(bf16x8*)(Fn2 + idx) = o;
}

// Upper-tri tiles: C = Fn*Fn^T -> exp -> masked row sums (+ col sums for
// off-diag by symmetry) -> atomics. Last block runs the finalize reduction.
__global__ __launch_bounds__(256, 4)
void cc_gemm(const short* __restrict__ Fn2, const int* __restrict__ cl,
             float* __restrict__ tot, float* __restrict__ pos,
             int* __restrict__ cnt, float* __restrict__ out) {
    __shared__ __align__(16) short As[KCHUNK_ELEMS];   // 16 KB
    __shared__ __align__(16) short Bs[KCHUNK_ELEMS];   // 16 KB
    __shared__ int crow[TILE], ccol[TILE];
    __shared__ float red[4];
    __shared__ int lastflag;

    const int tid  = threadIdx.x;
    const int wave = tid >> 6;
    const int lane = tid & 63;

    // decode upper-triangle block index -> (bm, bn), bm <= bn
    int rem = blockIdx.x, bm = 0;
    while (rem >= NTB - bm) { rem -= NTB - bm; ++bm; }
    const int bn = bm + rem;
    const bool diag = (bm == bn);

    if (tid < TILE)            crow[tid]        = cl[bm * TILE + tid];
    else                       ccol[tid - TILE] = cl[bn * TILE + (tid - TILE)];

    const int wr = wave >> 1, wc = wave & 1;    // 2x2 wave grid, 64x64 each
    const int q   = lane >> 4;
    const int n15 = lane & 15;

    f32x4 acc[4][4];
    #pragma unroll
    for (int t = 0; t < 4; ++t)
        #pragma unroll
        for (int u = 0; u < 4; ++u) acc[t][u] = (f32x4)(0.0f);

    const short* Ag = Fn2 + (size_t)bm * PANEL_ELEMS;
    const short* Bg = Fn2 + (size_t)bn * PANEL_ELEMS;

    for (int kc = 0; kc < NKC; ++kc) {
        __syncthreads();                         // LDS free (covers crow/ccol on kc=0)
        // stage 16 KB A + 16 KB B as pure linear copies: 4+4 x 1KB per wave
        const short* ga = Ag + kc * KCHUNK_ELEMS;
        const short* gb = Bg + kc * KCHUNK_ELEMS;
        #pragma unroll
        for (int i = 0; i < 4; ++i) {
            const int off = (wave * 4 + i) * 512;          // elems, 1 KB chunks
            gload_lds16(ga + off + lane * 8, As + off);
            gload_lds16(gb + off + lane * 8, Bs + off);
        }
        __syncthreads();                         // drain vmcnt before reads
        #pragma unroll
        for (int ks = 0; ks < 2; ++ks) {
            const int sub = ks * 4 + q;          // k = kc*64 + sub*8 + 0..7
            bf16x8 af[4], bfr[4];
            #pragma unroll
            for (int t = 0; t < 4; ++t)
                af[t] = *(const bf16x8*)&As[(sub * TILE + wr * 64 + t * 16 + n15) * 8];
            #pragma unroll
            for (int u = 0; u < 4; ++u)
                bfr[u] = *(const bf16x8*)&Bs[(sub * TILE + wc * 64 + u * 16 + n15) * 8];
            #pragma unroll
            for (int t = 0; t < 4; ++t)
                #pragma unroll
                for (int u = 0; u < 4; ++u)
                    acc[t][u] = __builtin_amdgcn_mfma_f32_16x16x32_bf16(af[t], bfr[u], acc[t][u], 0, 0, 0);
        }
    }

    // epilogue: e = exp(sim/T) = exp2(dot * 10*log2(e)); C layout col=lane&15, row=q*4+reg
    const float SC = 14.426950408889634f;
    int cc[4];
    #pragma unroll
    for (int u = 0; u < 4; ++u) cc[u] = ccol[wc * 64 + u * 16 + n15];

    float ce[4] = {0.f, 0.f, 0.f, 0.f};   // per-column (lane-local) sums
    float cp[4] = {0.f, 0.f, 0.f, 0.f};

    #pragma unroll
    for (int t = 0; t < 4; ++t) {
        #pragma unroll
        for (int r = 0; r < 4; ++r) {
            const int lr  = wr * 64 + t * 16 + q * 4 + r;   // local row
            const int myc = crow[lr];
            float te = 0.0f, tp = 0.0f;
            #pragma unroll
            for (int u = 0; u < 4; ++u) {
                const float e  = exp2f(acc[t][u][r] * SC);
                const float ep = (cc[u] == myc) ? e : 0.0f;
                te += e;  tp += ep;
                ce[u] += e;  cp[u] += ep;
            }
            #pragma unroll
            for (int m = 1; m < 16; m <<= 1) {   // reduce across 16 cols
                te += __shfl_xor(te, m, 64);
                tp += __shfl_xor(tp, m, 64);
            }
            if (n15 == 0) {
                const int grow = bm * TILE + lr;
                atomicAdd(&tot[grow], te);
                atomicAdd(&pos[grow], tp);
            }
        }
    }

    if (!diag) {
        // column sums -> rows of tile bn; column fixed per lane (n15), 2 stages over q
        #pragma unroll
        for (int u = 0; u < 4; ++u) {
            float e = ce[u], p = cp[u];
            e += __shfl_xor(e, 16, 64);  p += __shfl_xor(p, 16, 64);
            e += __shfl_xor(e, 32, 64);  p += __shfl_xor(p, 32, 64);
            if (lane < 16) {
                const int grow = bn * TILE + wc * 64 + u * 16 + n15;
                atomicAdd(&tot[grow], e);
                atomicAdd(&pos[grow], p);
            }
        }
    }

    // ---- fused finalize: last block reduces the loss ----
    __threadfence();          // release our atomics before counter bump
    __syncthreads();
    if (tid == 0) lastflag = (atomicAdd(cnt, 1) == NBLK - 1);
    __syncthreads();
    if (lastflag) {
        __threadfence();      // acquire
        float s = 0.0f;
        for (int i = tid; i < N; i += 256) {
            const float tv = __hip_atomic_load(&tot[i], __ATOMIC_RELAXED, __HIP_MEMORY_SCOPE_AGENT);
            const float pv = __hip_atomic_load(&pos[i], __ATOMIC_RELAXED, __HIP_MEMORY_SCOPE_AGENT);
            s += __logf(tv + 1e-8f) - __logf(pv);
        }
        #pragma unroll
        for (int m = 32; m; m >>= 1) s += __shfl_xor(s, m, 64);
        if (lane == 0) red[wave] = s;
        __syncthreads();
        if (tid == 0) out[0] = red[0] + red[1] + red[2] + red[3];
    }
}

extern "C" void kernel_launch(void* const* d_in, const int* in_sizes, int n_in,
                              void* d_out, int out_size, void* d_ws, size_t ws_size,
                              hipStream_t stream) {
    const float* F  = (const float*)d_in[0];
    const int*   cl = (const int*)d_in[1];
    float* out = (float*)d_out;

    short* Fn2 = (short*)d_ws;                                   // 8 MB swizzled
    float* tot = (float*)((char*)d_ws + (size_t)N * D * 2);      // 32 KB
    float* pos = tot + N;                                        // 32 KB
    int*   cnt = (int*)(pos + N);                                // 4 B done-counter

    cc_normalize<<<N / 4, 256, 0, stream>>>(F, Fn2, tot, cnt);
    cc_gemm<<<NBLK, 256, 0, stream>>>(Fn2, cl, tot, pos, cnt, out);
}

// Round 6
// 144.649 us; speedup vs baseline: 2.5439x; 2.5439x over previous
//
#include <hip/hip_runtime.h>
#include <hip/hip_bf16.h>
#include <stdint.h>

#define N 8192
#define D 512
#define TILE 128
#define BK 64
#define NKC (D / BK)                  // 8 K-chunks
#define NTB (N / TILE)                // 64 tile-rows (= #slices)
#define NBLK (NTB * (NTB + 1) / 2)    // 2080 upper-tri blocks
#define PANEL_ELEMS (TILE * D)        // 65536 elems = 128 KB per 128-row panel
#define KCHUNK_ELEMS (TILE * BK)      // 8192 elems = 16 KB per staged tile

typedef __attribute__((ext_vector_type(8))) short bf16x8;
typedef __attribute__((ext_vector_type(4))) float f32x4;

// async global->LDS, 16B per lane; LDS dest = wave-uniform base + lane*16
__device__ __forceinline__ void gload_lds16(const void* gp, const void* lp) {
    auto g = (const __attribute__((address_space(1))) void*)(uintptr_t)gp;
    auto l = (__attribute__((address_space(3))) void*)(uintptr_t)lp;
    __builtin_amdgcn_global_load_lds(g, l, 16, 0, 0);
}

__device__ __forceinline__ short f2bf(float x) {
    uint32_t u = __float_as_uint(x);
    u += 0x7fffu + ((u >> 16) & 1u);   // RNE; inputs finite/small
    return (short)(u >> 16);
}

// Fn2 swizzled = LDS tile image, linearized (R5 layout, verified):
//   elem(p, kc, sub, lr, ko) = p*65536 + ((kc*8+sub)*128 + lr)*8 + ko
// staging a (panel,kc) tile is a LINEAR 16 KB copy; LDS frag reads conflict-free.
__global__ void cc_normalize(const float* __restrict__ F, short* __restrict__ Fn2,
                             float* __restrict__ out) {
    if (blockIdx.x == 0 && threadIdx.x == 0) out[0] = 0.0f;   // finalize accumulates
    const int row  = blockIdx.x * 4 + (threadIdx.x >> 6);
    const int lane = threadIdx.x & 63;      // lane covers k = lane*8 .. +7
    const float* p = F + (size_t)row * D + lane * 8;
    float4 a = *(const float4*)p;
    float4 b = *(const float4*)(p + 4);
    float ss = a.x*a.x + a.y*a.y + a.z*a.z + a.w*a.w
             + b.x*b.x + b.y*b.y + b.z*b.z + b.w*b.w;
    #pragma unroll
    for (int m = 32; m; m >>= 1) ss += __shfl_xor(ss, m, 64);
    const float inv = 1.0f / fmaxf(sqrtf(ss), 1e-12f);
    bf16x8 o;
    o[0] = f2bf(a.x*inv); o[1] = f2bf(a.y*inv); o[2] = f2bf(a.z*inv); o[3] = f2bf(a.w*inv);
    o[4] = f2bf(b.x*inv); o[5] = f2bf(b.y*inv); o[6] = f2bf(b.z*inv); o[7] = f2bf(b.w*inv);
    const size_t idx = (size_t)(row >> 7) * PANEL_ELEMS + (size_t)lane * 1024 + (row & 127) * 8;
    *(bf16x8*)(Fn2 + idx) = o;
}

// Upper-tri tiles, LDS double-buffer, single barrier per K-step.
// NO atomics / NO fences: block (bm,bn) writes row-sums to slice bn and
// (off-diag) col-sums to slice bm of Pt/Pp — each slot has exactly one writer.
__global__ __launch_bounds__(256, 2)
void cc_gemm(const short* __restrict__ Fn2, const int* __restrict__ cl,
             float* __restrict__ Pt, float* __restrict__ Pp) {
    __shared__ __align__(16) short As[2][KCHUNK_ELEMS];   // 2 x 16 KB
    __shared__ __align__(16) short Bs[2][KCHUNK_ELEMS];   // 2 x 16 KB
    __shared__ int crow[TILE], ccol[TILE];
    __shared__ float rsum[2][TILE][2];   // [wc][row][te,tp]
    __shared__ float csum[2][TILE][2];   // [wr][col][te,tp]

    const int tid  = threadIdx.x;
    const int wave = tid >> 6;
    const int lane = tid & 63;

    int rem = blockIdx.x, bm = 0;
    while (rem >= NTB - bm) { rem -= NTB - bm; ++bm; }
    const int bn = bm + rem;
    const bool diag = (bm == bn);

    if (tid < TILE)            crow[tid]        = cl[bm * TILE + tid];
    else                       ccol[tid - TILE] = cl[bn * TILE + (tid - TILE)];

    const int wr = wave >> 1, wc = wave & 1;    // 2x2 wave grid, 64x64 each
    const int q   = lane >> 4;
    const int n15 = lane & 15;

    f32x4 acc[4][4];
    #pragma unroll
    for (int t = 0; t < 4; ++t)
        #pragma unroll
        for (int u = 0; u < 4; ++u) acc[t][u] = (f32x4)(0.0f);

    const short* Ag = Fn2 + (size_t)bm * PANEL_ELEMS;
    const short* Bg = Fn2 + (size_t)bn * PANEL_ELEMS;

    // prologue: stage kc=0 into buffer 0 (4+4 linear 1KB chunks per wave)
    #pragma unroll
    for (int i = 0; i < 4; ++i) {
        const int off = (wave * 4 + i) * 512;
        gload_lds16(Ag + off + lane * 8, &As[0][off]);
        gload_lds16(Bg + off + lane * 8, &Bs[0][off]);
    }

    for (int kc = 0; kc < NKC; ++kc) {
        const int b = kc & 1;
        __syncthreads();   // drains own vmcnt (stage issued one full phase ago)
        if (kc + 1 < NKC) {
            const short* ga = Ag + (kc + 1) * KCHUNK_ELEMS;
            const short* gb = Bg + (kc + 1) * KCHUNK_ELEMS;
            #pragma unroll
            for (int i = 0; i < 4; ++i) {
                const int off = (wave * 4 + i) * 512;
                gload_lds16(ga + off + lane * 8, &As[b ^ 1][off]);
                gload_lds16(gb + off + lane * 8, &Bs[b ^ 1][off]);
            }
        }
        #pragma unroll
        for (int ks = 0; ks < 2; ++ks) {
            const int sub = ks * 4 + q;          // k = kc*64 + sub*8 + 0..7
            bf16x8 af[4], bfr[4];
            #pragma unroll
            for (int t = 0; t < 4; ++t)
                af[t] = *(const bf16x8*)&As[b][(sub * TILE + wr * 64 + t * 16 + n15) * 8];
            #pragma unroll
            for (int u = 0; u < 4; ++u)
                bfr[u] = *(const bf16x8*)&Bs[b][(sub * TILE + wc * 64 + u * 16 + n15) * 8];
            #pragma unroll
            for (int t = 0; t < 4; ++t)
                #pragma unroll
                for (int u = 0; u < 4; ++u)
                    acc[t][u] = __builtin_amdgcn_mfma_f32_16x16x32_bf16(af[t], bfr[u], acc[t][u], 0, 0, 0);
        }
    }

    // epilogue: e = exp2(dot * 10*log2 e); C layout col=lane&15, row=q*4+reg
    const float SC = 14.426950408889634f;
    int cc[4];
    #pragma unroll
    for (int u = 0; u < 4; ++u) cc[u] = ccol[wc * 64 + u * 16 + n15];

    float ce[4] = {0.f, 0.f, 0.f, 0.f};
    float cp[4] = {0.f, 0.f, 0.f, 0.f};

    #pragma unroll
    for (int t = 0; t < 4; ++t) {
        #pragma unroll
        for (int r = 0; r < 4; ++r) {
            const int lr  = wr * 64 + t * 16 + q * 4 + r;
            const int myc = crow[lr];
            float te = 0.0f, tp = 0.0f;
            #pragma unroll
            for (int u = 0; u < 4; ++u) {
                const float e  = exp2f(acc[t][u][r] * SC);
                const float ep = (cc[u] == myc) ? e : 0.0f;
                te += e;  tp += ep;
                ce[u] += e;  cp[u] += ep;
            }
            #pragma unroll
            for (int m = 1; m < 16; m <<= 1) {
                te += __shfl_xor(te, m, 64);
                tp += __shfl_xor(tp, m, 64);
            }
            if (n15 == 0) { rsum[wc][lr][0] = te; rsum[wc][lr][1] = tp; }
        }
    }

    if (!diag) {
        #pragma unroll
        for (int u = 0; u < 4; ++u) {
            float e = ce[u], p = cp[u];
            e += __shfl_xor(e, 16, 64);  p += __shfl_xor(p, 16, 64);
            e += __shfl_xor(e, 32, 64);  p += __shfl_xor(p, 32, 64);
            if (lane < 16) {
                const int lc = wc * 64 + u * 16 + n15;
                csum[wr][lc][0] = e;  csum[wr][lc][1] = p;
            }
        }
    }

    __syncthreads();
    if (tid < TILE) {
        const float te = rsum[0][tid][0] + rsum[1][tid][0];
        const float tp = rsum[0][tid][1] + rsum[1][tid][1];
        const size_t o = (size_t)bn * N + bm * TILE + tid;
        Pt[o] = te;  Pp[o] = tp;
    } else if (!diag) {
        const int c = tid - TILE;
        const float te = csum[0][c][0] + csum[1][c][0];
        const float tp = csum[0][c][1] + csum[1][c][1];
        const size_t o = (size_t)bm * N + bn * TILE + c;
        Pt[o] = te;  Pp[o] = tp;
    }
}

// 32 blocks x 256: row i sums its 64 slices, loss, block-reduce, atomicAdd out
__global__ void cc_finalize(const float* __restrict__ Pt, const float* __restrict__ Pp,
                            float* __restrict__ out) {
    __shared__ float red[4];
    const int i = blockIdx.x * 256 + threadIdx.x;
    float tv = 0.0f, pv = 0.0f;
    #pragma unroll 8
    for (int s = 0; s < NTB; ++s) {
        tv += Pt[(size_t)s * N + i];
        pv += Pp[(size_t)s * N + i];
    }
    float l = __logf(tv + 1e-8f) - __logf(pv);
    #pragma unroll
    for (int m = 32; m; m >>= 1) l += __shfl_xor(l, m, 64);
    const int wv = threadIdx.x >> 6, lane = threadIdx.x & 63;
    if (lane == 0) red[wv] = l;
    __syncthreads();
    if (threadIdx.x == 0) atomicAdd(out, red[0] + red[1] + red[2] + red[3]);
}

extern "C" void kernel_launch(void* const* d_in, const int* in_sizes, int n_in,
                              void* d_out, int out_size, void* d_ws, size_t ws_size,
                              hipStream_t stream) {
    const float* F  = (const float*)d_in[0];
    const int*   cl = (const int*)d_in[1];
    float* out = (float*)d_out;

    short* Fn2 = (short*)d_ws;                                   // 8 MB swizzled
    float* Pt  = (float*)((char*)d_ws + (size_t)N * D * 2);      // 64*8192 f32 = 2 MB
    float* Pp  = Pt + (size_t)NTB * N;                           // 2 MB

    cc_normalize<<<N / 4, 256, 0, stream>>>(F, Fn2, out);
    cc_gemm<<<NBLK, 256, 0, stream>>>(Fn2, cl, Pt, Pp);
    cc_finalize<<<N / 256, 256, 0, stream>>>(Pt, Pp, out);
}

// Round 7
// 128.316 us; speedup vs baseline: 2.8677x; 1.1273x over previous
//
#include <hip/hip_runtime.h>
#include <hip/hip_bf16.h>
#include <stdint.h>

#define N 8192
#define D 512
#define TILE 128
#define BK 64
#define NKC (D / BK)                  // 8 K-chunks
#define NTB (N / TILE)                // 64 tile-rows (= #slices)
#define NBLK (NTB * (NTB + 1) / 2)    // 2080 upper-tri blocks
#define PANEL_BYTES (TILE * D)        // 65536 B per 128-row fp8 panel
#define KCHUNK_BYTES (TILE * BK)      // 8192 B per staged fp8 tile

typedef long long i64;
typedef __attribute__((ext_vector_type(4))) float f32x4;

// async global->LDS, 16B per lane; LDS dest = wave-uniform base + lane*16
__device__ __forceinline__ void gload_lds16(const void* gp, const void* lp) {
    auto g = (const __attribute__((address_space(1))) void*)(uintptr_t)gp;
    auto l = (__attribute__((address_space(3))) void*)(uintptr_t)lp;
    __builtin_amdgcn_global_load_lds(g, l, 16, 0, 0);
}

// Fn2 swizzled fp8 layout = LDS tile image, linearized (R5/R6 scheme, 1B elems):
//   byte(p, kc, ks, q, lr) = p*65536 + kc*8192 + ks*4096 + q*1024 + lr*8
// lane-group q holds k = kc*64 + ks*32 + q*8 .. +7 for row lr.
// Staging a (panel,kc) tile is a LINEAR 8 KB copy; LDS frag reads (b64) are
// bank-balanced (each bank exactly 4 requests per instr = minimum).
// Values stored as fp8_e4m3 of (16 * normalized_row): scale 16 centers the
// typical |entry|~0.044 at ~0.7, well inside e4m3 normal range.

__global__ void cc_normalize(const float* __restrict__ F, uint8_t* __restrict__ Fn2,
                             float* __restrict__ out) {
    if (blockIdx.x == 0 && threadIdx.x == 0) out[0] = 0.0f;   // finalize accumulates
    const int row  = blockIdx.x * 4 + (threadIdx.x >> 6);
    const int lane = threadIdx.x & 63;      // lane covers k = lane*8 .. +7
    const float* p = F + (size_t)row * D + lane * 8;
    float4 a = *(const float4*)p;
    float4 b = *(const float4*)(p + 4);
    float ss = a.x*a.x + a.y*a.y + a.z*a.z + a.w*a.w
             + b.x*b.x + b.y*b.y + b.z*b.z + b.w*b.w;
    #pragma unroll
    for (int m = 32; m; m >>= 1) ss += __shfl_xor(ss, m, 64);
    const float inv = 16.0f / fmaxf(sqrtf(ss), 1e-12f);   // scale 16 into fp8
    int lo = 0, hi = 0;
    lo = __builtin_amdgcn_cvt_pk_fp8_f32(a.x*inv, a.y*inv, lo, false);
    lo = __builtin_amdgcn_cvt_pk_fp8_f32(a.z*inv, a.w*inv, lo, true);
    hi = __builtin_amdgcn_cvt_pk_fp8_f32(b.x*inv, b.y*inv, hi, false);
    hi = __builtin_amdgcn_cvt_pk_fp8_f32(b.z*inv, b.w*inv, hi, true);
    const size_t idx = (size_t)(row >> 7) * PANEL_BYTES + (size_t)lane * 1024 + (row & 127) * 8;
    *(int2*)(Fn2 + idx) = make_int2(lo, hi);
}

// Upper-tri tiles, LDS double-buffer, single barrier per K-step, fp8 MFMA.
// NO atomics / NO fences: block (bm,bn) writes row-sums to slice bn and
// (off-diag) col-sums to slice bm of Pt/Pp — exactly one writer per slot.
__global__ __launch_bounds__(256, 4)
void cc_gemm(const uint8_t* __restrict__ Fn2, const int* __restrict__ cl,
             float* __restrict__ Pt, float* __restrict__ Pp) {
    __shared__ __align__(16) uint8_t As[2][KCHUNK_BYTES];   // 2 x 8 KB
    __shared__ __align__(16) uint8_t Bs[2][KCHUNK_BYTES];   // 2 x 8 KB
    __shared__ int crow[TILE], ccol[TILE];
    __shared__ float rsum[2][TILE][2];   // [wc][row][te,tp]
    __shared__ float csum[2][TILE][2];   // [wr][col][te,tp]

    const int tid  = threadIdx.x;
    const int wave = tid >> 6;
    const int lane = tid & 63;

    int rem = blockIdx.x, bm = 0;
    while (rem >= NTB - bm) { rem -= NTB - bm; ++bm; }
    const int bn = bm + rem;
    const bool diag = (bm == bn);

    if (tid < TILE)            crow[tid]        = cl[bm * TILE + tid];
    else                       ccol[tid - TILE] = cl[bn * TILE + (tid - TILE)];

    const int wr = wave >> 1, wc = wave & 1;    // 2x2 wave grid, 64x64 each
    const int q   = lane >> 4;
    const int n15 = lane & 15;

    f32x4 acc[4][4];
    #pragma unroll
    for (int t = 0; t < 4; ++t)
        #pragma unroll
        for (int u = 0; u < 4; ++u) acc[t][u] = (f32x4)(0.0f);

    const uint8_t* Ag = Fn2 + (size_t)bm * PANEL_BYTES;
    const uint8_t* Bg = Fn2 + (size_t)bn * PANEL_BYTES;

    // prologue: stage kc=0 into buffer 0 (2+2 linear 1KB chunks per wave)
    #pragma unroll
    for (int i = 0; i < 2; ++i) {
        const int off = (wave * 2 + i) * 1024;
        gload_lds16(Ag + off + lane * 16, &As[0][off]);
        gload_lds16(Bg + off + lane * 16, &Bs[0][off]);
    }

    for (int kc = 0; kc < NKC; ++kc) {
        const int b = kc & 1;
        __syncthreads();   // drains own vmcnt (stage issued one full phase ago)
        if (kc + 1 < NKC) {
            const uint8_t* ga = Ag + (kc + 1) * KCHUNK_BYTES;
            const uint8_t* gb = Bg + (kc + 1) * KCHUNK_BYTES;
            #pragma unroll
            for (int i = 0; i < 2; ++i) {
                const int off = (wave * 2 + i) * 1024;
                gload_lds16(ga + off + lane * 16, &As[b ^ 1][off]);
                gload_lds16(gb + off + lane * 16, &Bs[b ^ 1][off]);
            }
        }
        #pragma unroll
        for (int ks = 0; ks < 2; ++ks) {
            const int base = ks * 4096 + q * 1024 + n15 * 8;
            i64 af[4], bfr[4];
            #pragma unroll
            for (int t = 0; t < 4; ++t)
                af[t] = *(const i64*)&As[b][base + (wr * 64 + t * 16) * 8];
            #pragma unroll
            for (int u = 0; u < 4; ++u)
                bfr[u] = *(const i64*)&Bs[b][base + (wc * 64 + u * 16) * 8];
            #pragma unroll
            for (int t = 0; t < 4; ++t)
                #pragma unroll
                for (int u = 0; u < 4; ++u)
                    acc[t][u] = __builtin_amdgcn_mfma_f32_16x16x32_fp8_fp8(af[t], bfr[u], acc[t][u], 0, 0, 0);
        }
    }

    // epilogue: sim = dot/(16^2); e = exp(sim/T) = exp2(dot * 10*log2(e)/256)
    // C layout col=lane&15, row=q*4+reg
    const float SC = 0.05635527503472514f;
    int cc[4];
    #pragma unroll
    for (int u = 0; u < 4; ++u) cc[u] = ccol[wc * 64 + u * 16 + n15];

    float ce[4] = {0.f, 0.f, 0.f, 0.f};
    float cp[4] = {0.f, 0.f, 0.f, 0.f};

    #pragma unroll
    for (int t = 0; t < 4; ++t) {
        #pragma unroll
        for (int r = 0; r < 4; ++r) {
            const int lr  = wr * 64 + t * 16 + q * 4 + r;
            const int myc = crow[lr];
            float te = 0.0f, tp = 0.0f;
            #pragma unroll
            for (int u = 0; u < 4; ++u) {
                const float e  = exp2f(acc[t][u][r] * SC);
                const float ep = (cc[u] == myc) ? e : 0.0f;
                te += e;  tp += ep;
                ce[u] += e;  cp[u] += ep;
            }
            #pragma unroll
            for (int m = 1; m < 16; m <<= 1) {
                te += __shfl_xor(te, m, 64);
                tp += __shfl_xor(tp, m, 64);
            }
            if (n15 == 0) { rsum[wc][lr][0] = te; rsum[wc][lr][1] = tp; }
        }
    }

    if (!diag) {
        #pragma unroll
        for (int u = 0; u < 4; ++u) {
            float e = ce[u], p = cp[u];
            e += __shfl_xor(e, 16, 64);  p += __shfl_xor(p, 16, 64);
            e += __shfl_xor(e, 32, 64);  p += __shfl_xor(p, 32, 64);
            if (lane < 16) {
                const int lc = wc * 64 + u * 16 + n15;
                csum[wr][lc][0] = e;  csum[wr][lc][1] = p;
            }
        }
    }

    __syncthreads();
    if (tid < TILE) {
        const float te = rsum[0][tid][0] + rsum[1][tid][0];
        const float tp = rsum[0][tid][1] + rsum[1][tid][1];
        const size_t o = (size_t)bn * N + bm * TILE + tid;
        Pt[o] = te;  Pp[o] = tp;
    } else if (!diag) {
        const int c = tid - TILE;
        const float te = csum[0][c][0] + csum[1][c][0];
        const float tp = csum[0][c][1] + csum[1][c][1];
        const size_t o = (size_t)bm * N + bn * TILE + c;
        Pt[o] = te;  Pp[o] = tp;
    }
}

// 32 blocks x 256: row i sums its 64 slices, loss, block-reduce, atomicAdd out
__global__ void cc_finalize(const float* __restrict__ Pt, const float* __restrict__ Pp,
                            float* __restrict__ out) {
    __shared__ float red[4];
    const int i = blockIdx.x * 256 + threadIdx.x;
    float tv = 0.0f, pv = 0.0f;
    #pragma unroll 8
    for (int s = 0; s < NTB; ++s) {
        tv += Pt[(size_t)s * N + i];
        pv += Pp[(size_t)s * N + i];
    }
    float l = __logf(tv + 1e-8f) - __logf(pv);
    #pragma unroll
    for (int m = 32; m; m >>= 1) l += __shfl_xor(l, m, 64);
    const int wv = threadIdx.x >> 6, lane = threadIdx.x & 63;
    if (lane == 0) red[wv] = l;
    __syncthreads();
    if (threadIdx.x == 0) atomicAdd(out, red[0] + red[1] + red[2] + red[3]);
}

extern "C" void kernel_launch(void* const* d_in, const int* in_sizes, int n_in,
                              void* d_out, int out_size, void* d_ws, size_t ws_size,
                              hipStream_t stream) {
    const float* F  = (const float*)d_in[0];
    const int*   cl = (const int*)d_in[1];
    float* out = (float*)d_out;

    uint8_t* Fn2 = (uint8_t*)d_ws;                               // 4 MB fp8 swizzled
    float* Pt  = (float*)((char*)d_ws + (size_t)N * D);          // 64*8192 f32 = 2 MB
    float* Pp  = Pt + (size_t)NTB * N;                           // 2 MB

    cc_normalize<<<N / 4, 256, 0, stream>>>(F, Fn2, out);
    cc_gemm<<<NBLK, 256, 0, stream>>>(Fn2, cl, Pt, Pp);
    cc_finalize<<<N / 256, 256, 0, stream>>>(Pt, Pp, out);
}